// Round 8
// baseline (68305.127 us; speedup 1.0000x reference)
//
#include <hip/hip_runtime.h>

typedef unsigned short u16;
typedef unsigned int u32;
typedef unsigned long long u64;
typedef __bf16 bf16x8 __attribute__((ext_vector_type(8)));
typedef float f32x4 __attribute__((ext_vector_type(4)));

__device__ __forceinline__ u16 f2b(float f) {
  unsigned u = __float_as_uint(f);
  return (u16)((u + 0x7fffu + ((u >> 16) & 1u)) >> 16);
}
__device__ __forceinline__ float b2f(u16 h) {
  return __uint_as_float(((unsigned)h) << 16);
}

// LLC-coherent (agent-scope relaxed => sc-bit access, no cache-maintenance)
__device__ __forceinline__ void st_b16_llc(u16* p, u16 v) {
  __hip_atomic_store(p, v, __ATOMIC_RELAXED, __HIP_MEMORY_SCOPE_AGENT);
}
__device__ __forceinline__ bf16x8 ld_frag_llc(const u16* p) {
  union { u64 q[2]; bf16x8 v; } u;
  u.q[0] = __hip_atomic_load((const u64*)p,     __ATOMIC_RELAXED, __HIP_MEMORY_SCOPE_AGENT);
  u.q[1] = __hip_atomic_load((const u64*)p + 1, __ATOMIC_RELAXED, __HIP_MEMORY_SCOPE_AGENT);
  return u.v;
}

__global__ void cast_f32_bf16(const float* __restrict__ in, u16* __restrict__ out, int n) {
  int i = blockIdx.x * 256 + threadIdx.x;
  if (i < n) out[i] = f2b(in[i]);
}

// poll 32 group slots (lane<32, one slot each)
__device__ __forceinline__ void wait32(const unsigned* __restrict__ s, unsigned ep, int lane) {
  if (lane < 32)
    while (__hip_atomic_load(&s[lane], __ATOMIC_RELAXED, __HIP_MEMORY_SCOPE_AGENT) < ep) {}
}

// ---------------- tiled bf16 GEMM: C[M,N] = A[M,K] @ B[N,K]^T (fp32 out) ----------------
__global__ __launch_bounds__(256) void gemm_bt(
    const u16* __restrict__ A, const u16* __restrict__ B,
    int M, int N, int K,
    const float* __restrict__ bias, float* __restrict__ Cf)
{
  __shared__ u16 a_sm[128 * 32];
  __shared__ u16 b_sm[128 * 32];
  const int tid = threadIdx.x;
  const int lane = tid & 63;
  const int wid = tid >> 6;
  const int wm = wid >> 1, wn = wid & 1;
  const int m0 = blockIdx.x * 128, n0 = blockIdx.y * 128;
  const int q = lane >> 4, l15 = lane & 15, l3 = lane & 3;

  f32x4 acc[4][4];
  #pragma unroll
  for (int i = 0; i < 4; ++i)
    #pragma unroll
    for (int j = 0; j < 4; ++j) acc[i][j] = (f32x4){0.f, 0.f, 0.f, 0.f};

  for (int kk = 0; kk < K; kk += 32) {
    __syncthreads();
    #pragma unroll
    for (int p = 0; p < 2; ++p) {
      int idx = p * 256 + tid;
      int r = idx >> 2, cch = idx & 3;
      *(uint4*)&a_sm[r * 32 + ((cch ^ (r & 3)) * 8)] =
          *(const uint4*)&A[(size_t)(m0 + r) * K + kk + cch * 8];
      *(uint4*)&b_sm[r * 32 + ((cch ^ (r & 3)) * 8)] =
          *(const uint4*)&B[(size_t)(n0 + r) * K + kk + cch * 8];
    }
    __syncthreads();
    bf16x8 af[4], bfr[4];
    #pragma unroll
    for (int s = 0; s < 4; ++s) {
      int ra = wm * 64 + s * 16 + l15;
      af[s] = *(const bf16x8*)&a_sm[ra * 32 + ((q ^ l3) * 8)];
      int rb = wn * 64 + s * 16 + l15;
      bfr[s] = *(const bf16x8*)&b_sm[rb * 32 + ((q ^ l3) * 8)];
    }
    #pragma unroll
    for (int si = 0; si < 4; ++si)
      #pragma unroll
      for (int sj = 0; sj < 4; ++sj)
        acc[si][sj] = __builtin_amdgcn_mfma_f32_16x16x32_bf16(af[si], bfr[sj], acc[si][sj], 0, 0, 0);
  }

  #pragma unroll
  for (int si = 0; si < 4; ++si)
    #pragma unroll
    for (int sj = 0; sj < 4; ++sj)
      #pragma unroll
      for (int e = 0; e < 4; ++e) {
        int m = m0 + wm * 64 + si * 16 + q * 4 + e;
        int n = n0 + wn * 64 + sj * 16 + l15;
        Cf[(size_t)m * N + n] = acc[si][sj][e] + (bias ? bias[n] : 0.f);
      }
}

// ---------------- fused 2-layer GRU, directed group sync ----------------
// 64 wgs x 128 thr. wgs 0-31: layer0 (n-slice 32, K=1024+128); wgs 32-63:
// layer1 (n-slice 32, K=1024+1024, x-input = h0_t via depth-4 h0buf ring).
// Weights streamed from global (read-only -> per-XCD L2). h/rh via sc1/LLC.
// Epochs (init=1): after ph1(t) group posts 2t+2; after ph2(t) posts 2t+3.
// L0 ph2(t) overwrites h0buf[t&3], last read by L1 in ph2(t-4) which posts
// 2(t-4)+3 = 2t-5  -> back-pressure waits 2t-5 (2t-6 was the R7 race bug).
__global__ __launch_bounds__(128, 1) void gru_pipe(
    const u16* __restrict__ Wh0, const u16* __restrict__ Wx0,
    const u16* __restrict__ Wh1, const u16* __restrict__ Wx1,
    const float* __restrict__ bz0, const float* __restrict__ br0, const float* __restrict__ bg0,
    const float* __restrict__ bz1, const float* __restrict__ br1, const float* __restrict__ bg1,
    const u16* __restrict__ xb,                      // [32][512][128] bf16
    const float* __restrict__ h0p,                   // (32,2,1024) fp32
    u16* __restrict__ h0buf,                         // 4 x [32][1024] bf16 ring
    u16* __restrict__ hb1,                           // [32][1024]
    u16* __restrict__ rh0b, u16* __restrict__ rh1b,  // [32][1024]
    u16* __restrict__ seq1,                          // [32][512][1024] bf16
    float* __restrict__ hid,                         // (32,2,1024) fp32 out
    unsigned* __restrict__ slotsA,                   // 32 (L0)
    unsigned* __restrict__ slotsB)                   // 32 (L1)
{
  const int tid = threadIdx.x;
  const int lane = tid & 63;
  const int w = tid >> 6;
  const int bid = blockIdx.x;
  const bool Lyr1 = bid >= 32;
  const int gid = bid & 31;
  const int nb = gid * 32;
  const int q = lane >> 4, c15 = lane & 15, nl = c15 & 7;
  const bool isz = c15 < 8;
  const int brow = w * 16 + c15;

  // per-lane weight row pointers, 4 tiles of 8 n each
  const u16* pzh[4]; const u16* pzx[4]; const u16* pgh[4]; const u16* pgx[4];
  float bias1[4], bias2[4];
  const u16* Wh = Lyr1 ? Wh1 : Wh0;
  const u16* Wx = Lyr1 ? Wx1 : Wx0;
  const int IN = Lyr1 ? 1024 : 128;
  const size_t gate1 = isz ? 0u : 1u;
  #pragma unroll
  for (int j = 0; j < 4; ++j) {
    int row = nb + 8 * j + nl;
    pzh[j] = Wh + gate1 * 1048576 + (size_t)row * 1024;
    pzx[j] = Wx + gate1 * ((size_t)1024 * IN) + (size_t)row * IN;
    pgh[j] = Wh + (size_t)2 * 1048576 + (size_t)row * 1024;
    pgx[j] = Wx + (size_t)2 * ((size_t)1024 * IN) + (size_t)row * IN;
    bias1[j] = (isz ? (Lyr1 ? bz1 : bz0) : (Lyr1 ? br1 : br0))[row];
    bias2[j] = (Lyr1 ? bg1 : bg0)[row];
  }

  // ---- init: z-lanes hold h fp32 for (batch=b, n=nb+8j+nl); publish bf16 ----
  float hreg[4][4], zreg[4][4];
  #pragma unroll
  for (int j = 0; j < 4; ++j)
    #pragma unroll
    for (int e = 0; e < 4; ++e) {
      int b = w * 16 + q * 4 + e;
      int n = nb + 8 * j + nl;
      float v = h0p[b * 2048 + (Lyr1 ? 1024 : 0) + n];
      hreg[j][e] = v; zreg[j][e] = 0.f;
      if (isz)
        st_b16_llc((Lyr1 ? hb1 : h0buf + 3 * 32768) + b * 1024 + n, f2b(v));
    }
  __syncthreads();
  if (tid == 0)
    __hip_atomic_store(Lyr1 ? &slotsB[gid] : &slotsA[gid], 1u,
                       __ATOMIC_RELAXED, __HIP_MEMORY_SCOPE_AGENT);

  if (!Lyr1) {
    // =================== LAYER 0 ===================
    for (int t = 0; t < 512; ++t) {
      // ---- ph1: z,r ----
      if (w == 0) wait32(slotsA, 2 * t + 1, lane);
      __syncthreads();
      const u16* hp = h0buf + ((t + 3) & 3) * 32768;
      bf16x8 xf[4];
      #pragma unroll
      for (int jj = 0; jj < 4; ++jj)
        xf[jj] = *(const bf16x8*)&xb[((size_t)brow * 512 + t) * 128 + jj * 32 + q * 8];
      f32x4 a[4];
      #pragma unroll
      for (int j = 0; j < 4; ++j) a[j] = (f32x4){0.f, 0.f, 0.f, 0.f};
      #pragma unroll
      for (int ks = 0; ks < 32; ++ks) {
        bf16x8 af = ld_frag_llc(hp + (size_t)brow * 1024 + ks * 32 + q * 8);
        #pragma unroll
        for (int j = 0; j < 4; ++j)
          a[j] = __builtin_amdgcn_mfma_f32_16x16x32_bf16(af, *(const bf16x8*)&pzh[j][ks * 32 + q * 8], a[j], 0, 0, 0);
      }
      #pragma unroll
      for (int ks = 0; ks < 4; ++ks)
        #pragma unroll
        for (int j = 0; j < 4; ++j)
          a[j] = __builtin_amdgcn_mfma_f32_16x16x32_bf16(xf[ks], *(const bf16x8*)&pzx[j][ks * 32 + q * 8], a[j], 0, 0, 0);
      #pragma unroll
      for (int j = 0; j < 4; ++j)
        #pragma unroll
        for (int e = 0; e < 4; ++e) {
          float s = 1.f / (1.f + __expf(-(a[j][e] + bias1[j])));
          float hsh = __shfl_xor(hreg[j][e], 8);
          if (isz) zreg[j][e] = s;
          else st_b16_llc(&rh0b[(w * 16 + q * 4 + e) * 1024 + nb + 8 * j + nl], f2b(s * hsh));
        }
      __syncthreads();
      if (tid == 0)
        __hip_atomic_store(&slotsA[gid], 2u * t + 2, __ATOMIC_RELAXED, __HIP_MEMORY_SCOPE_AGENT);
      // ---- ph2: g, h' ----
      if (w == 0) {
        wait32(slotsA, 2 * t + 2, lane);
        if (t >= 4) wait32(slotsB, 2 * t - 5, lane);   // ring back-pressure (L1 done ph2(t-4))
      }
      __syncthreads();
      #pragma unroll
      for (int j = 0; j < 4; ++j) a[j] = (f32x4){0.f, 0.f, 0.f, 0.f};
      #pragma unroll
      for (int ks = 0; ks < 32; ++ks) {
        bf16x8 af = ld_frag_llc(rh0b + (size_t)brow * 1024 + ks * 32 + q * 8);
        #pragma unroll
        for (int j = 0; j < 4; ++j)
          a[j] = __builtin_amdgcn_mfma_f32_16x16x32_bf16(af, *(const bf16x8*)&pgh[j][ks * 32 + q * 8], a[j], 0, 0, 0);
      }
      #pragma unroll
      for (int ks = 0; ks < 4; ++ks)
        #pragma unroll
        for (int j = 0; j < 4; ++j)
          a[j] = __builtin_amdgcn_mfma_f32_16x16x32_bf16(xf[ks], *(const bf16x8*)&pgx[j][ks * 32 + q * 8], a[j], 0, 0, 0);
      if (isz) {
        u16* hout = h0buf + (t & 3) * 32768;
        #pragma unroll
        for (int j = 0; j < 4; ++j)
          #pragma unroll
          for (int e = 0; e < 4; ++e) {
            int b = w * 16 + q * 4 + e;
            int n = nb + 8 * j + nl;
            float ex = __expf(2.f * (a[j][e] + bias2[j]));
            float gv = 1.f - 2.f / (ex + 1.f);
            float hn = zreg[j][e] * hreg[j][e] + (1.f - zreg[j][e]) * gv;
            hreg[j][e] = hn;
            st_b16_llc(&hout[b * 1024 + n], f2b(hn));
            if (t == 511) hid[b * 2048 + n] = hn;
          }
      }
      __syncthreads();
      if (tid == 0)
        __hip_atomic_store(&slotsA[gid], 2u * t + 3, __ATOMIC_RELAXED, __HIP_MEMORY_SCOPE_AGENT);
    }
  } else {
    // =================== LAYER 1 ===================
    for (int s = 0; s < 512; ++s) {
      // ---- ph1 ----
      if (w == 0) {
        wait32(slotsB, 2 * s + 1, lane);
        wait32(slotsA, 2 * s + 3, lane);               // h0buf[s&3] ready
      }
      __syncthreads();
      const u16* hp = h0buf + (s & 3) * 32768;
      f32x4 a[4];
      #pragma unroll
      for (int j = 0; j < 4; ++j) a[j] = (f32x4){0.f, 0.f, 0.f, 0.f};
      #pragma unroll
      for (int ks = 0; ks < 32; ++ks) {
        bf16x8 af = ld_frag_llc(hb1 + (size_t)brow * 1024 + ks * 32 + q * 8);
        #pragma unroll
        for (int j = 0; j < 4; ++j)
          a[j] = __builtin_amdgcn_mfma_f32_16x16x32_bf16(af, *(const bf16x8*)&pzh[j][ks * 32 + q * 8], a[j], 0, 0, 0);
      }
      #pragma unroll
      for (int ks = 0; ks < 32; ++ks) {
        bf16x8 af = ld_frag_llc(hp + (size_t)brow * 1024 + ks * 32 + q * 8);
        #pragma unroll
        for (int j = 0; j < 4; ++j)
          a[j] = __builtin_amdgcn_mfma_f32_16x16x32_bf16(af, *(const bf16x8*)&pzx[j][(ks + 32) * 32 + q * 8 - 1024], a[j], 0, 0, 0);
      }
      #pragma unroll
      for (int j = 0; j < 4; ++j)
        #pragma unroll
        for (int e = 0; e < 4; ++e) {
          float sg = 1.f / (1.f + __expf(-(a[j][e] + bias1[j])));
          float hsh = __shfl_xor(hreg[j][e], 8);
          if (isz) zreg[j][e] = sg;
          else st_b16_llc(&rh1b[(w * 16 + q * 4 + e) * 1024 + nb + 8 * j + nl], f2b(sg * hsh));
        }
      __syncthreads();
      if (tid == 0)
        __hip_atomic_store(&slotsB[gid], 2u * s + 2, __ATOMIC_RELAXED, __HIP_MEMORY_SCOPE_AGENT);
      // ---- ph2 ----
      if (w == 0) wait32(slotsB, 2 * s + 2, lane);
      __syncthreads();
      #pragma unroll
      for (int j = 0; j < 4; ++j) a[j] = (f32x4){0.f, 0.f, 0.f, 0.f};
      #pragma unroll
      for (int ks = 0; ks < 32; ++ks) {
        bf16x8 af = ld_frag_llc(rh1b + (size_t)brow * 1024 + ks * 32 + q * 8);
        #pragma unroll
        for (int j = 0; j < 4; ++j)
          a[j] = __builtin_amdgcn_mfma_f32_16x16x32_bf16(af, *(const bf16x8*)&pgh[j][ks * 32 + q * 8], a[j], 0, 0, 0);
      }
      #pragma unroll
      for (int ks = 0; ks < 32; ++ks) {
        bf16x8 af = ld_frag_llc(hp + (size_t)brow * 1024 + ks * 32 + q * 8);
        #pragma unroll
        for (int j = 0; j < 4; ++j)
          a[j] = __builtin_amdgcn_mfma_f32_16x16x32_bf16(af, *(const bf16x8*)&pgx[j][(ks + 32) * 32 + q * 8 - 1024], a[j], 0, 0, 0);
      }
      if (isz) {
        #pragma unroll
        for (int j = 0; j < 4; ++j)
          #pragma unroll
          for (int e = 0; e < 4; ++e) {
            int b = w * 16 + q * 4 + e;
            int n = nb + 8 * j + nl;
            float ex = __expf(2.f * (a[j][e] + bias2[j]));
            float gv = 1.f - 2.f / (ex + 1.f);
            float hn = zreg[j][e] * hreg[j][e] + (1.f - zreg[j][e]) * gv;
            hreg[j][e] = hn;
            u16 hnb = f2b(hn);
            st_b16_llc(&hb1[b * 1024 + n], hnb);
            seq1[((size_t)b * 512 + s) * 1024 + n] = hnb;
            if (s == 511) hid[1024 + b * 2048 + n] = hn;
          }
      }
      __syncthreads();
      if (tid == 0)
        __hip_atomic_store(&slotsB[gid], 2u * s + 3, __ATOMIC_RELAXED, __HIP_MEMORY_SCOPE_AGENT);
    }
  }
}

// ---------------- host ----------------
extern "C" void kernel_launch(void* const* d_in, const int* in_sizes, int n_in,
                              void* d_out, int out_size, void* d_ws, size_t ws_size,
                              hipStream_t stream) {
  (void)in_sizes; (void)n_in; (void)out_size; (void)ws_size;
  char* ws = (char*)d_ws;
  const size_t MB = 1024ull * 1024ull;
  u16* seq1 = (u16*)(ws + 0);                         // 32 MB
  u16* xb   = (u16*)(ws + 32 * MB);                   // 4 MB
  u16* Wh0  = (u16*)(ws + 36 * MB);                   // 6 MB
  u16* Wh1  = (u16*)(ws + 42 * MB);                   // 6 MB
  u16* Wx0  = (u16*)(ws + 48 * MB);                   // 0.75 MB
  u16* Wx1  = (u16*)(ws + 49 * MB);                   // 6 MB
  u16* Wyb  = (u16*)(ws + 55 * MB);                   // 0.25 MB
  u16* h0buf = (u16*)(ws + 56 * MB);                  // 4 x 64 KB ring
  u16* hb1  = (u16*)(ws + 56 * MB + 256 * 1024);      // 64 KB
  u16* rh0b = (u16*)(ws + 56 * MB + 320 * 1024);      // 64 KB
  u16* rh1b = (u16*)(ws + 56 * MB + 384 * 1024);      // 64 KB
  unsigned* slotsA = (unsigned*)(ws + 56 * MB + 448 * 1024);  // 128 B
  unsigned* slotsB = slotsA + 128;                             // +512 B

  hipMemsetAsync(slotsA, 0, 1024, stream);

  auto cast = [&](const void* in, u16* out, int n) {
    cast_f32_bf16<<<(n + 255) / 256, 256, 0, stream>>>((const float*)in, out, n);
  };
  cast(d_in[0], xb, 2097152);                               // x
  cast(d_in[3],  Wh0 + 0,       1048576);                   // Whz0
  cast(d_in[6],  Wh0 + 1048576, 1048576);                   // Whr0
  cast(d_in[9],  Wh0 + 2097152, 1048576);                   // Whg0
  cast(d_in[12], Wh1 + 0,       1048576);                   // Whz1
  cast(d_in[15], Wh1 + 1048576, 1048576);                   // Whr1
  cast(d_in[18], Wh1 + 2097152, 1048576);                   // Whg1
  cast(d_in[2],  Wx0 + 0,      131072);                     // Wxz0
  cast(d_in[5],  Wx0 + 131072, 131072);                     // Wxr0
  cast(d_in[8],  Wx0 + 262144, 131072);                     // Wxg0
  cast(d_in[11], Wx1 + 0,       1048576);                   // Wxz1
  cast(d_in[14], Wx1 + 1048576, 1048576);                   // Wxr1
  cast(d_in[17], Wx1 + 2097152, 1048576);                   // Wxg1
  cast(d_in[20], Wyb, 131072);                              // Wy

  float* y_out = (float*)d_out;
  float* hid = y_out + 2097152;                             // hidden (32,2,1024)

  gru_pipe<<<64, dim3(128), 0, stream>>>(
      Wh0, Wx0, Wh1, Wx1,
      (const float*)d_in[4],  (const float*)d_in[7],  (const float*)d_in[10],
      (const float*)d_in[13], (const float*)d_in[16], (const float*)d_in[19],
      xb, (const float*)d_in[1],
      h0buf, hb1, rh0b, rh1b, seq1, hid, slotsA, slotsB);

  // output projection y = seq1 @ Wy^T + by  (M=16384, N=128, K=1024)
  gemm_bt<<<dim3(128, 1), dim3(256), 0, stream>>>(
      seq1, Wyb, 16384, 128, 1024, (const float*)d_in[21], y_out);
}

// Round 9
// 25858.679 us; speedup vs baseline: 2.6415x; 2.6415x over previous
//
#include <hip/hip_runtime.h>

typedef unsigned short u16;
typedef unsigned int u32;
typedef unsigned long long u64;
typedef __bf16 bf16x8 __attribute__((ext_vector_type(8)));
typedef float f32x4 __attribute__((ext_vector_type(4)));

__device__ __forceinline__ u16 f2b(float f) {
  unsigned u = __float_as_uint(f);
  return (u16)((u + 0x7fffu + ((u >> 16) & 1u)) >> 16);
}
__device__ __forceinline__ float b2f(u16 h) {
  return __uint_as_float(((unsigned)h) << 16);
}

__device__ __forceinline__ void st_u32_llc(u32* p, u32 v) {
  __hip_atomic_store(p, v, __ATOMIC_RELAXED, __HIP_MEMORY_SCOPE_AGENT);
}

// ---- tagged granule: 8 u32 = 8 bf16 values (hi16) each carrying epoch (lo16) ----
struct Gran { u64 q[4]; };
__device__ __forceinline__ Gran ld_gran(const u32* p) {
  Gran g;
  #pragma unroll
  for (int i = 0; i < 4; ++i)
    g.q[i] = __hip_atomic_load((const u64*)p + 2 * i * 0 + i, __ATOMIC_RELAXED, __HIP_MEMORY_SCOPE_AGENT);
  return g;
}
__device__ __forceinline__ bool gran_ok(const Gran& g, unsigned ep) {
  u64 pat = (u64)ep | ((u64)ep << 32);
  u64 t = 0;
  #pragma unroll
  for (int i = 0; i < 4; ++i) t |= (g.q[i] ^ pat) & 0x0000FFFF0000FFFFull;
  return t == 0;
}
__device__ __forceinline__ bf16x8 gran_pack(const Gran& g) {
  union { u32 d[4]; bf16x8 v; } r;
  #pragma unroll
  for (int i = 0; i < 4; ++i) {
    u32 lo = (u32)g.q[i], hi = (u32)(g.q[i] >> 32);
    r.d[i] = (lo >> 16) | (hi & 0xFFFF0000u);
  }
  return r.v;
}

// pipelined tagged MFMA stream: N granules (N=32 one buffer, N=64 two buffers
// back-to-back: g<32 from sb0/ep0, g>=32 from sb1/ep1). B-frags from LDS.
template <int N>
__device__ __forceinline__ f32x4 mfma_streamN(const u32* sb0, const u32* sb1,
                                              unsigned ep0, unsigned ep1,
                                              const u16* bbase, int bstep, f32x4 acc) {
  Gran pipe[8];
  #pragma unroll
  for (int d = 0; d < 8 && d < N; ++d) {
    const u32* p = (d < 32) ? sb0 + d * 32 : sb1 + (d - 32) * 32;
    pipe[d & 7] = ld_gran(p);
  }
  #pragma unroll
  for (int g = 0; g < N; ++g) {
    const u32* pg = (g < 32) ? sb0 + g * 32 : sb1 + (g - 32) * 32;
    unsigned ep = (g < 32) ? ep0 : ep1;
    Gran gr = pipe[g & 7];
    while (!gran_ok(gr, ep)) gr = ld_gran(pg);
    if (g + 8 < N) {
      int n2 = g + 8;
      const u32* pn = (n2 < 32) ? sb0 + n2 * 32 : sb1 + (n2 - 32) * 32;
      pipe[g & 7] = ld_gran(pn);
    }
    acc = __builtin_amdgcn_mfma_f32_16x16x32_bf16(gran_pack(gr),
              *(const bf16x8*)(bbase + g * bstep), acc, 0, 0, 0);
  }
  return acc;
}

// ---------------- generic fp32 -> bf16 cast ----------------
__global__ void cast_f32_bf16(const float* __restrict__ in, u16* __restrict__ out, int n) {
  int i = blockIdx.x * 256 + threadIdx.x;
  if (i < n) out[i] = f2b(in[i]);
}

// ---------------- tiled bf16 GEMM: C[M,N] = A[M,K] @ B[N,K]^T (fp32 out) ----------------
__global__ __launch_bounds__(256) void gemm_bt(
    const u16* __restrict__ A, const u16* __restrict__ B,
    int M, int N, int K,
    const float* __restrict__ bias, float* __restrict__ Cf)
{
  __shared__ u16 a_sm[128 * 32];
  __shared__ u16 b_sm[128 * 32];
  const int tid = threadIdx.x;
  const int lane = tid & 63;
  const int wid = tid >> 6;
  const int wm = wid >> 1, wn = wid & 1;
  const int m0 = blockIdx.x * 128, n0 = blockIdx.y * 128;
  const int q = lane >> 4, l15 = lane & 15, l3 = lane & 3;

  f32x4 acc[4][4];
  #pragma unroll
  for (int i = 0; i < 4; ++i)
    #pragma unroll
    for (int j = 0; j < 4; ++j) acc[i][j] = (f32x4){0.f, 0.f, 0.f, 0.f};

  for (int kk = 0; kk < K; kk += 32) {
    __syncthreads();
    #pragma unroll
    for (int p = 0; p < 2; ++p) {
      int idx = p * 256 + tid;
      int r = idx >> 2, cch = idx & 3;
      *(uint4*)&a_sm[r * 32 + ((cch ^ (r & 3)) * 8)] =
          *(const uint4*)&A[(size_t)(m0 + r) * K + kk + cch * 8];
      *(uint4*)&b_sm[r * 32 + ((cch ^ (r & 3)) * 8)] =
          *(const uint4*)&B[(size_t)(n0 + r) * K + kk + cch * 8];
    }
    __syncthreads();
    bf16x8 af[4], bfr[4];
    #pragma unroll
    for (int s = 0; s < 4; ++s) {
      int ra = wm * 64 + s * 16 + l15;
      af[s] = *(const bf16x8*)&a_sm[ra * 32 + ((q ^ l3) * 8)];
      int rb = wn * 64 + s * 16 + l15;
      bfr[s] = *(const bf16x8*)&b_sm[rb * 32 + ((q ^ l3) * 8)];
    }
    #pragma unroll
    for (int si = 0; si < 4; ++si)
      #pragma unroll
      for (int sj = 0; sj < 4; ++sj)
        acc[si][sj] = __builtin_amdgcn_mfma_f32_16x16x32_bf16(af[si], bfr[sj], acc[si][sj], 0, 0, 0);
  }

  #pragma unroll
  for (int si = 0; si < 4; ++si)
    #pragma unroll
    for (int sj = 0; sj < 4; ++sj)
      #pragma unroll
      for (int e = 0; e < 4; ++e) {
        int m = m0 + wm * 64 + si * 16 + q * 4 + e;
        int n = n0 + wn * 64 + sj * 16 + l15;
        Cf[(size_t)m * N + n] = acc[si][sj][e] + (bias ? bias[n] : 0.f);
      }
}

// ---------------- fused 2-layer GRU, barrier-free tag-in-data protocol ----------------
// 256 wgs x 128 thr. wgs 0-127: layer 0 (n-slice 8, K=1024+128, weights in LDS).
// wgs 128-255: layer 1 (n-slice 8, K=1024+1024 concat, x-input = h0 via depth-4 ring).
// All shared state published as u32 = (bf16<<16)|epoch via relaxed agent stores;
// consumers poll the exact granules they feed to MFMA (exact-tag match; 0xAA
// poison never matches). No barriers. Ring back-pressure via doneB[128] only.
// Tags: h0 ring slot t&3 = t+1 (init slot3=0); rh0 = t+1; hb1 holds h1(s-1) tag s;
// rh1 = s+1; doneB[gid] = s+1 after L1 ph2(s); L0 ph2(t>=4) needs doneB >= t-3.
__global__ __launch_bounds__(128, 1) void gru_pipe(
    const u16* __restrict__ Wh0, const u16* __restrict__ Wx0,
    const u16* __restrict__ Wh1, const u16* __restrict__ Wx1,
    const float* __restrict__ bz0, const float* __restrict__ br0, const float* __restrict__ bg0,
    const float* __restrict__ bz1, const float* __restrict__ br1, const float* __restrict__ bg1,
    const u16* __restrict__ xb,                      // [32][512][128] bf16
    const float* __restrict__ h0p,                   // (32,2,1024) fp32
    u32* __restrict__ h0ring,                        // 4 x [32][1024] tagged
    u32* __restrict__ hb1,                           // [32][1024] tagged
    u32* __restrict__ rh0, u32* __restrict__ rh1,    // [32][1024] tagged
    u16* __restrict__ seq1,                          // [32][512][1024] bf16
    float* __restrict__ hid,                         // (32,2,1024) fp32 out
    u32* __restrict__ doneB)                         // 128 completion slots (memset 0)
{
  __shared__ u16 zr_frag[64 * 512];                  // B-frag order, 64 KB
  __shared__ u16 g_frag[64 * 256];                   // 32 KB

  const int tid = threadIdx.x;
  const int lane = tid & 63;
  const int w = tid >> 6;
  const int bid = blockIdx.x;
  const bool Lyr1 = bid >= 128;
  const int gid = bid & 127;
  const int nb = gid * 8;
  const int q = lane >> 4, c15 = lane & 15, nl = c15 & 7;
  const int n_own = nb + nl;
  const bool isz = c15 < 8;
  const int brow = w * 16 + c15;
  const int KS = Lyr1 ? 64 : 36;
  const int IN = Lyr1 ? 1024 : 128;
  const u16* Wh = Lyr1 ? Wh1 : Wh0;
  const u16* Wx = Lyr1 ? Wx1 : Wx0;
  const size_t WXG = (size_t)1024 * IN;

  // ---- stage concat [Wh | Wx] weights into LDS in MFMA B-frag order (R6-verified) ----
  for (int cidx = tid; cidx < KS * 64; cidx += 128) {
    int ks = cidx >> 6, l = cidx & 63;
    int lq = l >> 4, lc = l & 15;
    int row = nb + (lc & 7), gate = (lc < 8) ? 0 : 1;  // z | r
    int k0 = ks * 32 + lq * 8;
    const u16* src = (k0 < 1024)
        ? Wh + (size_t)gate * 1048576 + (size_t)row * 1024 + k0
        : Wx + (size_t)gate * WXG + (size_t)row * IN + (k0 - 1024);
    *(uint4*)&zr_frag[cidx * 8] = *(const uint4*)src;
  }
  for (int gidx = tid; gidx < KS * 32; gidx += 128) {
    int ks = gidx >> 5, s = gidx & 31;
    int lq = s >> 3, r8 = s & 7;
    int row = nb + r8, k0 = ks * 32 + lq * 8;
    const u16* src = (k0 < 1024)
        ? Wh + (size_t)2 * 1048576 + (size_t)row * 1024 + k0
        : Wx + (size_t)2 * WXG + (size_t)row * IN + (k0 - 1024);
    *(uint4*)&g_frag[gidx * 8] = *(const uint4*)src;
  }

  const float bias1 = isz ? (Lyr1 ? bz1 : bz0)[n_own] : (Lyr1 ? br1 : br0)[n_own];
  const float bias2 = (Lyr1 ? bg1 : bg0)[n_own];

  // ---- init: z-lanes hold h fp32; publish tagged (epoch 0) ----
  float hreg[4], zreg[4] = {0.f, 0.f, 0.f, 0.f};
  #pragma unroll
  for (int e = 0; e < 4; ++e) {
    int b = w * 16 + q * 4 + e;
    float v = h0p[b * 2048 + (Lyr1 ? 1024 : 0) + n_own];
    hreg[e] = v;
    if (isz) {
      u32 word = ((u32)f2b(v) << 16) | 0u;
      st_u32_llc((Lyr1 ? hb1 : h0ring + 3 * 32768) + b * 1024 + n_own, word);
    }
  }
  __syncthreads();                                   // LDS staging complete

  const int soff = brow * 1024 + q * 8;              // state granule base offset
  const u16* bzr = &zr_frag[lane * 8];
  const u16* bgf = &g_frag[(q * 8 + nl) * 8];

  if (!Lyr1) {
    // =================== LAYER 0 ===================
    bf16x8 xf[4];
    for (int t = 0; t < 512; ++t) {
      // ---- ph1: z,r  (reads h0(t-1): ring slot (t-1)&3, tag t) ----
      #pragma unroll
      for (int jj = 0; jj < 4; ++jj)
        xf[jj] = *(const bf16x8*)&xb[((size_t)brow * 512 + t) * 128 + jj * 32 + q * 8];
      const u32* slot_r = h0ring + ((t + 3) & 3) * 32768 + soff;
      f32x4 a = {0.f, 0.f, 0.f, 0.f};
      a = mfma_streamN<32>(slot_r, slot_r, (unsigned)t, (unsigned)t, bzr, 512, a);
      #pragma unroll
      for (int ks = 0; ks < 4; ++ks)
        a = __builtin_amdgcn_mfma_f32_16x16x32_bf16(xf[ks],
                *(const bf16x8*)&zr_frag[(32 + ks) * 512 + lane * 8], a, 0, 0, 0);
      #pragma unroll
      for (int e = 0; e < 4; ++e) {
        float sg = 1.f / (1.f + __expf(-(a[e] + bias1)));
        float hsh = __shfl_xor(hreg[e], 8);
        if (isz) zreg[e] = sg;
        else {
          int b = w * 16 + q * 4 + e;
          u32 word = ((u32)f2b(sg * hsh) << 16) | (u32)(t + 1);
          st_u32_llc(&rh0[b * 1024 + n_own], word);
        }
      }
      // ---- ph2: g, h'  (reads rh0 tag t+1) ----
      const u32* rs = rh0 + soff;
      f32x4 g2 = {0.f, 0.f, 0.f, 0.f};
      g2 = mfma_streamN<32>(rs, rs, (unsigned)(t + 1), (unsigned)(t + 1), bgf, 256, g2);
      #pragma unroll
      for (int ks = 0; ks < 4; ++ks)
        g2 = __builtin_amdgcn_mfma_f32_16x16x32_bf16(xf[ks],
                 *(const bf16x8*)&g_frag[(32 + ks) * 256 + (q * 8 + nl) * 8], g2, 0, 0, 0);
      if (t >= 4) {                                  // ring back-pressure: L1 done ph2(t-4)
        unsigned need = (unsigned)(t - 3);
        while (__hip_atomic_load(&doneB[lane], __ATOMIC_RELAXED, __HIP_MEMORY_SCOPE_AGENT) < need) {}
        while (__hip_atomic_load(&doneB[64 + lane], __ATOMIC_RELAXED, __HIP_MEMORY_SCOPE_AGENT) < need) {}
      }
      if (isz) {
        u32* hout = h0ring + (t & 3) * 32768;
        #pragma unroll
        for (int e = 0; e < 4; ++e) {
          int b = w * 16 + q * 4 + e;
          float ex = __expf(2.f * (g2[e] + bias2));
          float gv = 1.f - 2.f / (ex + 1.f);         // tanh, overflow-safe
          float hn = zreg[e] * hreg[e] + (1.f - zreg[e]) * gv;
          hreg[e] = hn;
          u32 word = ((u32)f2b(hn) << 16) | (u32)(t + 1);
          st_u32_llc(&hout[b * 1024 + n_own], word);
          if (t == 511) hid[b * 2048 + n_own] = hn;
        }
      }
    }
  } else {
    // =================== LAYER 1 ===================
    for (int s = 0; s < 512; ++s) {
      const u32* slot = h0ring + (s & 3) * 32768 + soff;
      // ---- ph1: z,r  (hb1 tag s, h0 slot tag s+1) ----
      const u32* hs = hb1 + soff;
      f32x4 a = {0.f, 0.f, 0.f, 0.f};
      a = mfma_streamN<64>(hs, slot, (unsigned)s, (unsigned)(s + 1), bzr, 512, a);
      #pragma unroll
      for (int e = 0; e < 4; ++e) {
        float sg = 1.f / (1.f + __expf(-(a[e] + bias1)));
        float hsh = __shfl_xor(hreg[e], 8);
        if (isz) zreg[e] = sg;
        else {
          int b = w * 16 + q * 4 + e;
          u32 word = ((u32)f2b(sg * hsh) << 16) | (u32)(s + 1);
          st_u32_llc(&rh1[b * 1024 + n_own], word);
        }
      }
      // ---- ph2: g, h'  (rh1 tag s+1, h0 slot tag s+1) ----
      const u32* rs = rh1 + soff;
      f32x4 g2 = {0.f, 0.f, 0.f, 0.f};
      g2 = mfma_streamN<64>(rs, slot, (unsigned)(s + 1), (unsigned)(s + 1), bgf, 256, g2);
      if (isz) {
        #pragma unroll
        for (int e = 0; e < 4; ++e) {
          int b = w * 16 + q * 4 + e;
          float ex = __expf(2.f * (g2[e] + bias2));
          float gv = 1.f - 2.f / (ex + 1.f);
          float hn = zreg[e] * hreg[e] + (1.f - zreg[e]) * gv;
          hreg[e] = hn;
          u16 hnb = f2b(hn);
          u32 word = ((u32)hnb << 16) | (u32)(s + 1);
          st_u32_llc(&hb1[b * 1024 + n_own], word);
          seq1[((size_t)b * 512 + s) * 1024 + n_own] = hnb;
          if (s == 511) hid[1024 + b * 2048 + n_own] = hn;
        }
      }
      __syncthreads();                               // both waves' ring reads retired
      if (tid == 0)
        __hip_atomic_store(&doneB[gid], (u32)(s + 1), __ATOMIC_RELAXED, __HIP_MEMORY_SCOPE_AGENT);
    }
  }
}

// ---------------- host ----------------
extern "C" void kernel_launch(void* const* d_in, const int* in_sizes, int n_in,
                              void* d_out, int out_size, void* d_ws, size_t ws_size,
                              hipStream_t stream) {
  (void)in_sizes; (void)n_in; (void)out_size; (void)ws_size;
  char* ws = (char*)d_ws;
  const size_t MB = 1024ull * 1024ull;
  u16* seq1 = (u16*)(ws + 0);                         // 32 MB
  u16* xb   = (u16*)(ws + 32 * MB);                   // 4 MB
  u16* Wh0  = (u16*)(ws + 36 * MB);                   // 6 MB
  u16* Wh1  = (u16*)(ws + 42 * MB);                   // 6 MB
  u16* Wx0  = (u16*)(ws + 48 * MB);                   // 0.75 MB
  u16* Wx1  = (u16*)(ws + 49 * MB);                   // 6 MB
  u16* Wyb  = (u16*)(ws + 55 * MB);                   // 0.25 MB
  u32* h0ring = (u32*)(ws + 56 * MB);                 // 512 KB (4 slots, tagged)
  u32* hb1  = (u32*)(ws + 56 * MB + 512 * 1024);      // 128 KB
  u32* rh0  = (u32*)(ws + 56 * MB + 640 * 1024);      // 128 KB
  u32* rh1  = (u32*)(ws + 56 * MB + 768 * 1024);      // 128 KB
  u32* doneB = (u32*)(ws + 56 * MB + 896 * 1024);     // 512 B

  hipMemsetAsync(doneB, 0, 512, stream);

  auto cast = [&](const void* in, u16* out, int n) {
    cast_f32_bf16<<<(n + 255) / 256, 256, 0, stream>>>((const float*)in, out, n);
  };
  cast(d_in[0], xb, 2097152);                               // x
  cast(d_in[3],  Wh0 + 0,       1048576);                   // Whz0
  cast(d_in[6],  Wh0 + 1048576, 1048576);                   // Whr0
  cast(d_in[9],  Wh0 + 2097152, 1048576);                   // Whg0
  cast(d_in[12], Wh1 + 0,       1048576);                   // Whz1
  cast(d_in[15], Wh1 + 1048576, 1048576);                   // Whr1
  cast(d_in[18], Wh1 + 2097152, 1048576);                   // Whg1
  cast(d_in[2],  Wx0 + 0,      131072);                     // Wxz0
  cast(d_in[5],  Wx0 + 131072, 131072);                     // Wxr0
  cast(d_in[8],  Wx0 + 262144, 131072);                     // Wxg0
  cast(d_in[11], Wx1 + 0,       1048576);                   // Wxz1
  cast(d_in[14], Wx1 + 1048576, 1048576);                   // Wxr1
  cast(d_in[17], Wx1 + 2097152, 1048576);                   // Wxg1
  cast(d_in[20], Wyb, 131072);                              // Wy

  float* y_out = (float*)d_out;
  float* hid = y_out + 2097152;                             // hidden (32,2,1024)

  gru_pipe<<<256, dim3(128), 0, stream>>>(
      Wh0, Wx0, Wh1, Wx1,
      (const float*)d_in[4],  (const float*)d_in[7],  (const float*)d_in[10],
      (const float*)d_in[13], (const float*)d_in[16], (const float*)d_in[19],
      xb, (const float*)d_in[1],
      h0ring, hb1, rh0, rh1, seq1, hid, doneB);

  // output projection y = seq1 @ Wy^T + by  (M=16384, N=128, K=1024)
  gemm_bt<<<dim3(128, 1), dim3(256), 0, stream>>>(
      seq1, Wyb, 16384, 128, 1024, (const float*)d_in[21], y_out);
}

// Round 10
// 11692.524 us; speedup vs baseline: 5.8418x; 2.2116x over previous
//
#include <hip/hip_runtime.h>

typedef unsigned short u16;
typedef unsigned int u32;
typedef unsigned long long u64;
typedef __bf16 bf16x8 __attribute__((ext_vector_type(8)));
typedef float f32x4 __attribute__((ext_vector_type(4)));

__device__ __forceinline__ u16 f2b(float f) {
  unsigned u = __float_as_uint(f);
  return (u16)((u + 0x7fffu + ((u >> 16) & 1u)) >> 16);
}
__device__ __forceinline__ float b2f(u16 h) {
  return __uint_as_float(((unsigned)h) << 16);
}

// LLC-coherent (agent-scope relaxed => sc-bit access, no cache-maintenance)
__device__ __forceinline__ void st_b16_llc(u16* p, u16 v) {
  __hip_atomic_store(p, v, __ATOMIC_RELAXED, __HIP_MEMORY_SCOPE_AGENT);
}
__device__ __forceinline__ bf16x8 ld_frag_llc(const u16* p) {
  union { u64 q[2]; bf16x8 v; } u;
  u.q[0] = __hip_atomic_load((const u64*)p,     __ATOMIC_RELAXED, __HIP_MEMORY_SCOPE_AGENT);
  u.q[1] = __hip_atomic_load((const u64*)p + 1, __ATOMIC_RELAXED, __HIP_MEMORY_SCOPE_AGENT);
  return u.v;
}

__global__ void cast_f32_bf16(const float* __restrict__ in, u16* __restrict__ out, int n) {
  int i = blockIdx.x * 256 + threadIdx.x;
  if (i < n) out[i] = f2b(in[i]);
}

// wave-0 poll of a 128-slot domain (2 slots per lane)
__device__ __forceinline__ void wait128(const u32* __restrict__ s, u32 ep, int lane) {
  while (__hip_atomic_load(&s[lane],      __ATOMIC_RELAXED, __HIP_MEMORY_SCOPE_AGENT) < ep) {}
  while (__hip_atomic_load(&s[64 + lane], __ATOMIC_RELAXED, __HIP_MEMORY_SCOPE_AGENT) < ep) {}
}

// ---------------- tiled bf16 GEMM: C[M,N] = A[M,K] @ B[N,K]^T (fp32 out) ----------------
__global__ __launch_bounds__(256) void gemm_bt(
    const u16* __restrict__ A, const u16* __restrict__ B,
    int M, int N, int K,
    const float* __restrict__ bias, float* __restrict__ Cf)
{
  __shared__ u16 a_sm[128 * 32];
  __shared__ u16 b_sm[128 * 32];
  const int tid = threadIdx.x;
  const int lane = tid & 63;
  const int wid = tid >> 6;
  const int wm = wid >> 1, wn = wid & 1;
  const int m0 = blockIdx.x * 128, n0 = blockIdx.y * 128;
  const int q = lane >> 4, l15 = lane & 15, l3 = lane & 3;

  f32x4 acc[4][4];
  #pragma unroll
  for (int i = 0; i < 4; ++i)
    #pragma unroll
    for (int j = 0; j < 4; ++j) acc[i][j] = (f32x4){0.f, 0.f, 0.f, 0.f};

  for (int kk = 0; kk < K; kk += 32) {
    __syncthreads();
    #pragma unroll
    for (int p = 0; p < 2; ++p) {
      int idx = p * 256 + tid;
      int r = idx >> 2, cch = idx & 3;
      *(uint4*)&a_sm[r * 32 + ((cch ^ (r & 3)) * 8)] =
          *(const uint4*)&A[(size_t)(m0 + r) * K + kk + cch * 8];
      *(uint4*)&b_sm[r * 32 + ((cch ^ (r & 3)) * 8)] =
          *(const uint4*)&B[(size_t)(n0 + r) * K + kk + cch * 8];
    }
    __syncthreads();
    bf16x8 af[4], bfr[4];
    #pragma unroll
    for (int s = 0; s < 4; ++s) {
      int ra = wm * 64 + s * 16 + l15;
      af[s] = *(const bf16x8*)&a_sm[ra * 32 + ((q ^ l3) * 8)];
      int rb = wn * 64 + s * 16 + l15;
      bfr[s] = *(const bf16x8*)&b_sm[rb * 32 + ((q ^ l3) * 8)];
    }
    #pragma unroll
    for (int si = 0; si < 4; ++si)
      #pragma unroll
      for (int sj = 0; sj < 4; ++sj)
        acc[si][sj] = __builtin_amdgcn_mfma_f32_16x16x32_bf16(af[si], bfr[sj], acc[si][sj], 0, 0, 0);
  }

  #pragma unroll
  for (int si = 0; si < 4; ++si)
    #pragma unroll
    for (int sj = 0; sj < 4; ++sj)
      #pragma unroll
      for (int e = 0; e < 4; ++e) {
        int m = m0 + wm * 64 + si * 16 + q * 4 + e;
        int n = n0 + wn * 64 + sj * 16 + l15;
        Cf[(size_t)m * N + n] = acc[si][sj][e] + (bias ? bias[n] : 0.f);
      }
}

// ---------------- fused 2-layer GRU, split sync domains + x-precompute ----------------
// 256 wgs x 128 thr. wgs 0-127 = L0 (n-slice 8, LDS concat [Wh0|Wx0], K=1152).
// wgs 128-255 = L1 (n-slice 8, LDS = Wh1 only (48 KB); x-part h0@Wx1 precomputed
// one step ahead into regs, B-frags streamed from global/L2, A from h0 ring).
// Domains: slotsA (L0), slotsB (L1), 128 slots each. Epochs (init 1):
// post 2t+2 after ph1(t), 2t+3 after ph2(t). Cross edges: L1 x(s) needs
// slotsA>=2s+3; L0 ph2(t>=4) needs slotsB>=2t-5 (ring, R8-verified).
__global__ __launch_bounds__(128, 1) void gru_pipe(
    const u16* __restrict__ Wh0, const u16* __restrict__ Wx0,
    const u16* __restrict__ Wh1, const u16* __restrict__ Wx1,
    const float* __restrict__ bz0, const float* __restrict__ br0, const float* __restrict__ bg0,
    const float* __restrict__ bz1, const float* __restrict__ br1, const float* __restrict__ bg1,
    const u16* __restrict__ xb,                      // [32][512][128] bf16
    const float* __restrict__ h0p,                   // (32,2,1024) fp32
    u16* __restrict__ h0ring,                        // 4 x [32][1024] bf16 ring
    u16* __restrict__ hb1,                           // [32][1024]
    u16* __restrict__ rh0, u16* __restrict__ rh1,    // [32][1024]
    u16* __restrict__ seq1,                          // [32][512][1024] bf16
    float* __restrict__ hid,                         // (32,2,1024) fp32 out
    u32* __restrict__ slotsA, u32* __restrict__ slotsB)
{
  __shared__ u16 zr_frag[36 * 512];                  // L0: 36 KB used; L1: 32 KB
  __shared__ u16 g_frag[36 * 256];                   // L0: 18 KB; L1: 16 KB

  const int tid = threadIdx.x;
  const int lane = tid & 63;
  const int w = tid >> 6;
  const int bid = blockIdx.x;
  const bool Lyr1 = bid >= 128;
  const int gid = bid & 127;
  const int nb = gid * 8;
  const int q = lane >> 4, c15 = lane & 15, nl = c15 & 7;
  const int n_own = nb + nl;
  const bool isz = c15 < 8;
  const int brow = w * 16 + c15;
  const int KS = Lyr1 ? 32 : 36;
  const u16* Wh = Lyr1 ? Wh1 : Wh0;

  // ---- stage weights into LDS in MFMA B-frag order (R6-verified layout) ----
  for (int cidx = tid; cidx < KS * 64; cidx += 128) {
    int ks = cidx >> 6, l = cidx & 63;
    int lq = l >> 4, lc = l & 15;
    int row = nb + (lc & 7), gate = (lc < 8) ? 0 : 1;  // z | r
    int k0 = ks * 32 + lq * 8;
    const u16* src = (k0 < 1024)
        ? Wh + (size_t)gate * 1048576 + (size_t)row * 1024 + k0
        : Wx0 + (size_t)gate * 131072 + (size_t)row * 128 + (k0 - 1024);  // L0 only
    *(uint4*)&zr_frag[cidx * 8] = *(const uint4*)src;
  }
  for (int gidx = tid; gidx < KS * 32; gidx += 128) {
    int ks = gidx >> 5, sl = gidx & 31;
    int lq = sl >> 3, r8 = sl & 7;
    int row = nb + r8, k0 = ks * 32 + lq * 8;
    const u16* src = (k0 < 1024)
        ? Wh + (size_t)2 * 1048576 + (size_t)row * 1024 + k0
        : Wx0 + (size_t)2 * 131072 + (size_t)row * 128 + (k0 - 1024);     // L0 only
    *(uint4*)&g_frag[gidx * 8] = *(const uint4*)src;
  }

  const float bias1 = isz ? (Lyr1 ? bz1 : bz0)[n_own] : (Lyr1 ? br1 : br0)[n_own];
  const float bias2 = (Lyr1 ? bg1 : bg0)[n_own];

  // ---- init: z-lanes hold h fp32; publish bf16 (L0 -> ring slot 3, L1 -> hb1) ----
  float hreg[4], zreg[4] = {0.f, 0.f, 0.f, 0.f};
  #pragma unroll
  for (int e = 0; e < 4; ++e) {
    int b = w * 16 + q * 4 + e;
    float v = h0p[b * 2048 + (Lyr1 ? 1024 : 0) + n_own];
    hreg[e] = v;
    if (isz)
      st_b16_llc((Lyr1 ? hb1 : h0ring + 3 * 32768) + b * 1024 + n_own, f2b(v));
  }
  __syncthreads();
  if (tid == 0)
    __hip_atomic_store(Lyr1 ? &slotsB[gid] : &slotsA[gid], 1u,
                       __ATOMIC_RELAXED, __HIP_MEMORY_SCOPE_AGENT);

  if (!Lyr1) {
    // =================== LAYER 0 (domain A) ===================
    for (int t = 0; t < 512; ++t) {
      // ---- ph1: z,r ----
      if (w == 0) wait128(slotsA, 2u * t + 1, lane);
      __syncthreads();
      const u16* hp = h0ring + ((t + 3) & 3) * 32768 + (size_t)brow * 1024;
      bf16x8 xf[4];
      #pragma unroll
      for (int jj = 0; jj < 4; ++jj)
        xf[jj] = *(const bf16x8*)&xb[((size_t)brow * 512 + t) * 128 + jj * 32 + q * 8];
      f32x4 a = {0.f, 0.f, 0.f, 0.f};
      #pragma unroll
      for (int ks = 0; ks < 32; ++ks)
        a = __builtin_amdgcn_mfma_f32_16x16x32_bf16(ld_frag_llc(hp + ks * 32 + q * 8),
                *(const bf16x8*)&zr_frag[ks * 512 + lane * 8], a, 0, 0, 0);
      #pragma unroll
      for (int ks = 0; ks < 4; ++ks)
        a = __builtin_amdgcn_mfma_f32_16x16x32_bf16(xf[ks],
                *(const bf16x8*)&zr_frag[(32 + ks) * 512 + lane * 8], a, 0, 0, 0);
      #pragma unroll
      for (int e = 0; e < 4; ++e) {
        float sg = 1.f / (1.f + __expf(-(a[e] + bias1)));
        float hsh = __shfl_xor(hreg[e], 8);
        if (isz) zreg[e] = sg;
        else st_b16_llc(&rh0[(w * 16 + q * 4 + e) * 1024 + n_own], f2b(sg * hsh));
      }
      __syncthreads();
      if (tid == 0)
        __hip_atomic_store(&slotsA[gid], 2u * t + 2, __ATOMIC_RELAXED, __HIP_MEMORY_SCOPE_AGENT);
      // ---- ph2: g, h' ----
      if (w == 0) {
        wait128(slotsA, 2u * t + 2, lane);
        if (t >= 4) wait128(slotsB, 2u * t - 5, lane);   // ring back-pressure (R8-verified)
      }
      __syncthreads();
      f32x4 g2 = {0.f, 0.f, 0.f, 0.f};
      const u16* rp = rh0 + (size_t)brow * 1024;
      #pragma unroll
      for (int ks = 0; ks < 32; ++ks)
        g2 = __builtin_amdgcn_mfma_f32_16x16x32_bf16(ld_frag_llc(rp + ks * 32 + q * 8),
                 *(const bf16x8*)&g_frag[ks * 256 + (q * 8 + nl) * 8], g2, 0, 0, 0);
      #pragma unroll
      for (int ks = 0; ks < 4; ++ks)
        g2 = __builtin_amdgcn_mfma_f32_16x16x32_bf16(xf[ks],
                 *(const bf16x8*)&g_frag[(32 + ks) * 256 + (q * 8 + nl) * 8], g2, 0, 0, 0);
      if (isz) {
        u16* hout = h0ring + (t & 3) * 32768;
        #pragma unroll
        for (int e = 0; e < 4; ++e) {
          int b = w * 16 + q * 4 + e;
          float ex = __expf(2.f * (g2[e] + bias2));
          float gv = 1.f - 2.f / (ex + 1.f);             // tanh, overflow-safe
          float hn = zreg[e] * hreg[e] + (1.f - zreg[e]) * gv;
          hreg[e] = hn;
          st_b16_llc(&hout[b * 1024 + n_own], f2b(hn));
          if (t == 511) hid[b * 2048 + n_own] = hn;
        }
      }
      __syncthreads();
      if (tid == 0)
        __hip_atomic_store(&slotsA[gid], 2u * t + 3, __ATOMIC_RELAXED, __HIP_MEMORY_SCOPE_AGENT);
    }
  } else {
    // =================== LAYER 1 (domain B) ===================
    // x-part B-frag pointers (global, L2-resident, read-only)
    const u16* pzx1 = Wx1 + (size_t)(isz ? 0 : 1) * 1048576 + (size_t)n_own * 1024;
    const u16* pgx1 = Wx1 + (size_t)2 * 1048576 + (size_t)n_own * 1024;

    f32x4 xzr_cur = {0.f, 0.f, 0.f, 0.f}, xg_cur = {0.f, 0.f, 0.f, 0.f};
    f32x4 xzr_nxt = {0.f, 0.f, 0.f, 0.f}, xg_nxt = {0.f, 0.f, 0.f, 0.f};
    // pre-loop: x(0) from h0 ring slot 0 (needs slotsA >= 3)
    if (w == 0) wait128(slotsA, 3u, lane);
    __syncthreads();
    {
      const u16* hp = h0ring + (size_t)brow * 1024;    // slot 0
      #pragma unroll
      for (int ks = 0; ks < 32; ++ks) {
        bf16x8 af = ld_frag_llc(hp + ks * 32 + q * 8);
        xzr_cur = __builtin_amdgcn_mfma_f32_16x16x32_bf16(af, *(const bf16x8*)&pzx1[ks * 32 + q * 8], xzr_cur, 0, 0, 0);
        xg_cur  = __builtin_amdgcn_mfma_f32_16x16x32_bf16(af, *(const bf16x8*)&pgx1[ks * 32 + q * 8], xg_cur, 0, 0, 0);
      }
    }
    for (int s = 0; s < 512; ++s) {
      // ---- (a) ph1: z,r (recurrent half only) ----
      if (w == 0) wait128(slotsB, 2u * s + 1, lane);
      __syncthreads();
      const u16* hp1 = hb1 + (size_t)brow * 1024;
      f32x4 a = xzr_cur;
      #pragma unroll
      for (int ks = 0; ks < 32; ++ks)
        a = __builtin_amdgcn_mfma_f32_16x16x32_bf16(ld_frag_llc(hp1 + ks * 32 + q * 8),
                *(const bf16x8*)&zr_frag[ks * 512 + lane * 8], a, 0, 0, 0);
      #pragma unroll
      for (int e = 0; e < 4; ++e) {
        float sg = 1.f / (1.f + __expf(-(a[e] + bias1)));
        float hsh = __shfl_xor(hreg[e], 8);
        if (isz) zreg[e] = sg;
        else st_b16_llc(&rh1[(w * 16 + q * 4 + e) * 1024 + n_own], f2b(sg * hsh));
      }
      __syncthreads();
      if (tid == 0)
        __hip_atomic_store(&slotsB[gid], 2u * s + 2, __ATOMIC_RELAXED, __HIP_MEMORY_SCOPE_AGENT);
      // ---- (b) x-zr precompute for s+1 (hides ph2 sync) ----
      if (s < 511) {
        if (w == 0) wait128(slotsA, 2u * s + 5, lane);  // h0(s+1) ready
        __syncthreads();
        const u16* hp = h0ring + ((s + 1) & 3) * 32768 + (size_t)brow * 1024;
        f32x4 acc = {0.f, 0.f, 0.f, 0.f};
        #pragma unroll
        for (int ks = 0; ks < 32; ++ks)
          acc = __builtin_amdgcn_mfma_f32_16x16x32_bf16(ld_frag_llc(hp + ks * 32 + q * 8),
                    *(const bf16x8*)&pzx1[ks * 32 + q * 8], acc, 0, 0, 0);
        xzr_nxt = acc;
      }
      // ---- (c) ph2: g, h' (recurrent half only) ----
      if (w == 0) wait128(slotsB, 2u * s + 2, lane);
      __syncthreads();
      const u16* rp = rh1 + (size_t)brow * 1024;
      f32x4 g2 = xg_cur;
      #pragma unroll
      for (int ks = 0; ks < 32; ++ks)
        g2 = __builtin_amdgcn_mfma_f32_16x16x32_bf16(ld_frag_llc(rp + ks * 32 + q * 8),
                 *(const bf16x8*)&g_frag[ks * 256 + (q * 8 + nl) * 8], g2, 0, 0, 0);
      if (isz) {
        #pragma unroll
        for (int e = 0; e < 4; ++e) {
          int b = w * 16 + q * 4 + e;
          float ex = __expf(2.f * (g2[e] + bias2));
          float gv = 1.f - 2.f / (ex + 1.f);
          float hn = zreg[e] * hreg[e] + (1.f - zreg[e]) * gv;
          hreg[e] = hn;
          u16 hnb = f2b(hn);
          st_b16_llc(&hb1[b * 1024 + n_own], hnb);
          seq1[((size_t)b * 512 + s) * 1024 + n_own] = hnb;
          if (s == 511) hid[1024 + b * 2048 + n_own] = hn;
        }
      }
      __syncthreads();
      if (tid == 0)
        __hip_atomic_store(&slotsB[gid], 2u * s + 3, __ATOMIC_RELAXED, __HIP_MEMORY_SCOPE_AGENT);
      // ---- (d) x-g precompute for s+1 (hides next ph1 sync) ----
      if (s < 511) {
        const u16* hp = h0ring + ((s + 1) & 3) * 32768 + (size_t)brow * 1024;
        f32x4 acc = {0.f, 0.f, 0.f, 0.f};
        #pragma unroll
        for (int ks = 0; ks < 32; ++ks)
          acc = __builtin_amdgcn_mfma_f32_16x16x32_bf16(ld_frag_llc(hp + ks * 32 + q * 8),
                    *(const bf16x8*)&pgx1[ks * 32 + q * 8], acc, 0, 0, 0);
        xg_nxt = acc;
        xzr_cur = xzr_nxt;
        xg_cur = xg_nxt;
      }
    }
  }
}

// ---------------- host ----------------
extern "C" void kernel_launch(void* const* d_in, const int* in_sizes, int n_in,
                              void* d_out, int out_size, void* d_ws, size_t ws_size,
                              hipStream_t stream) {
  (void)in_sizes; (void)n_in; (void)out_size; (void)ws_size;
  char* ws = (char*)d_ws;
  const size_t MB = 1024ull * 1024ull;
  u16* seq1 = (u16*)(ws + 0);                         // 32 MB
  u16* xb   = (u16*)(ws + 32 * MB);                   // 4 MB
  u16* Wh0  = (u16*)(ws + 36 * MB);                   // 6 MB
  u16* Wh1  = (u16*)(ws + 42 * MB);                   // 6 MB
  u16* Wx0  = (u16*)(ws + 48 * MB);                   // 0.75 MB
  u16* Wx1  = (u16*)(ws + 49 * MB);                   // 6 MB
  u16* Wyb  = (u16*)(ws + 55 * MB);                   // 0.25 MB
  u16* h0ring = (u16*)(ws + 56 * MB);                 // 4 x 64 KB ring
  u16* hb1  = (u16*)(ws + 56 * MB + 256 * 1024);      // 64 KB
  u16* rh0  = (u16*)(ws + 56 * MB + 320 * 1024);      // 64 KB
  u16* rh1  = (u16*)(ws + 56 * MB + 384 * 1024);      // 64 KB
  u32* slotsA = (u32*)(ws + 56 * MB + 448 * 1024);    // 512 B
  u32* slotsB = slotsA + 128;                         // 512 B

  hipMemsetAsync(slotsA, 0, 1024, stream);

  auto cast = [&](const void* in, u16* out, int n) {
    cast_f32_bf16<<<(n + 255) / 256, 256, 0, stream>>>((const float*)in, out, n);
  };
  cast(d_in[0], xb, 2097152);                               // x
  cast(d_in[3],  Wh0 + 0,       1048576);                   // Whz0
  cast(d_in[6],  Wh0 + 1048576, 1048576);                   // Whr0
  cast(d_in[9],  Wh0 + 2097152, 1048576);                   // Whg0
  cast(d_in[12], Wh1 + 0,       1048576);                   // Whz1
  cast(d_in[15], Wh1 + 1048576, 1048576);                   // Whr1
  cast(d_in[18], Wh1 + 2097152, 1048576);                   // Whg1
  cast(d_in[2],  Wx0 + 0,      131072);                     // Wxz0
  cast(d_in[5],  Wx0 + 131072, 131072);                     // Wxr0
  cast(d_in[8],  Wx0 + 262144, 131072);                     // Wxg0
  cast(d_in[11], Wx1 + 0,       1048576);                   // Wxz1
  cast(d_in[14], Wx1 + 1048576, 1048576);                   // Wxr1
  cast(d_in[17], Wx1 + 2097152, 1048576);                   // Wxg1
  cast(d_in[20], Wyb, 131072);                              // Wy

  float* y_out = (float*)d_out;
  float* hid = y_out + 2097152;                             // hidden (32,2,1024)

  gru_pipe<<<256, dim3(128), 0, stream>>>(
      Wh0, Wx0, Wh1, Wx1,
      (const float*)d_in[4],  (const float*)d_in[7],  (const float*)d_in[10],
      (const float*)d_in[13], (const float*)d_in[16], (const float*)d_in[19],
      xb, (const float*)d_in[1],
      h0ring, hb1, rh0, rh1, seq1, hid, slotsA, slotsB);

  // output projection y = seq1 @ Wy^T + by  (M=16384, N=128, K=1024)
  gemm_bt<<<dim3(128, 1), dim3(256), 0, stream>>>(
      seq1, Wyb, 16384, 128, 1024, (const float*)d_in[21], y_out);
}